// Round 8
// baseline (180.264 us; speedup 1.0000x reference)
//
#include <hip/hip_runtime.h>
#include <math.h>

#define RAD 20
#define KLEN 41
#define NH 1024
#define NW 2048
#define NHW (NH * NW)

// ---- Compile-time Gaussian-derivative weights (fp64, matches numpy) ----
struct KW { float w[KLEN]; };
constexpr double cexp_neg(double u) {  // exp(-u), 0 <= u <= 0.5
  double term = 1.0, sum = 1.0;
  for (int k = 1; k < 30; ++k) { term *= (-u) / (double)k; sum += term; }
  return sum;
}
constexpr KW make_kw() {
  KW r{};
  double ph[KLEN] = {};
  double s = 0.0;
  for (int i = 0; i < KLEN; ++i) {
    double d = (double)(i - RAD);
    double e = cexp_neg(d * d / 800.0);
    e = e * e; e = e * e; e = e * e; e = e * e;  // ^16
    ph[i] = e; s += e;
  }
  for (int i = 0; i < KLEN; ++i) {
    double d = (double)(i - RAD);
    r.w[i] = (float)((-d / 25.0) * (ph[i] / s) / 2.27);
  }
  return r;
}
static constexpr KW KWC = make_kw();

// Tap-major conv core, 8-accumulator form.
template <int K>
__device__ __forceinline__ void tap(float s, float& r0, float& r1, float& r2,
                                    float& r3, float& r4, float& r5, float& r6,
                                    float& r7) {
  if constexpr (K - 0 >= 0 && K - 0 <= 40) r0 = fmaf(s, KWC.w[K - 0], r0);
  if constexpr (K - 1 >= 0 && K - 1 <= 40) r1 = fmaf(s, KWC.w[K - 1], r1);
  if constexpr (K - 2 >= 0 && K - 2 <= 40) r2 = fmaf(s, KWC.w[K - 2], r2);
  if constexpr (K - 3 >= 0 && K - 3 <= 40) r3 = fmaf(s, KWC.w[K - 3], r3);
  if constexpr (K - 4 >= 0 && K - 4 <= 40) r4 = fmaf(s, KWC.w[K - 4], r4);
  if constexpr (K - 5 >= 0 && K - 5 <= 40) r5 = fmaf(s, KWC.w[K - 5], r5);
  if constexpr (K - 6 >= 0 && K - 6 <= 40) r6 = fmaf(s, KWC.w[K - 6], r6);
  if constexpr (K - 7 >= 0 && K - 7 <= 40) r7 = fmaf(s, KWC.w[K - 7], r7);
}

#define R8 r0, r1, r2, r3, r4, r5, r6, r7

#define TW 64  // tile width (x)
#define TH 32  // output rows per block
#define TILE_CH ((TH + 2 * RAD) * TW)  // 72*64 = 4608 floats per channel slot

// Column conv along y within a staged channel tile (same chunk/tap order as
// the original k_dy -> bit-identical dY results).
__device__ __forceinline__ void conv_col(const float* __restrict__ t, int base,
                                         int lane, float& r0, float& r1,
                                         float& r2, float& r3, float& r4,
                                         float& r5, float& r6, float& r7) {
#define CCHUNK(c)                                      \
  {                                                    \
    float s0 = t[(base + 4 * (c) + 0) * TW + lane];    \
    float s1 = t[(base + 4 * (c) + 1) * TW + lane];    \
    float s2 = t[(base + 4 * (c) + 2) * TW + lane];    \
    float s3 = t[(base + 4 * (c) + 3) * TW + lane];    \
    tap<4 * (c) + 0>(s0, R8);                          \
    tap<4 * (c) + 1>(s1, R8);                          \
    tap<4 * (c) + 2>(s2, R8);                          \
    tap<4 * (c) + 3>(s3, R8);                          \
  }
  CCHUNK(0) CCHUNK(1) CCHUNK(2) CCHUNK(3) CCHUNK(4) CCHUNK(5)
  CCHUNK(6) CCHUNK(7) CCHUNK(8) CCHUNK(9) CCHUNK(10) CCHUNK(11)
#undef CCHUNK
}

// m_0 numerator: sum over pixels of ||m||_F (fp32 sqrt, fp64 accumulate).
__global__ __launch_bounds__(256) void k_reduce(const float* __restrict__ y,
                                                double* __restrict__ acc) {
  const int tid = blockIdx.x * blockDim.x + threadIdx.x;
  const int stride = gridDim.x * blockDim.x;
  double local = 0.0;
  for (int q = tid; q < NHW / 4; q += stride) {
    float4 a = ((const float4*)y)[q];
    float4 b = ((const float4*)(y + NHW))[q];
    float4 c = ((const float4*)(y + 2 * (size_t)NHW))[q];
    float4 d = ((const float4*)(y + 3 * (size_t)NHW))[q];
    local += (double)sqrtf(a.x * a.x + b.x * b.x + c.x * c.x + d.x * d.x);
    local += (double)sqrtf(a.y * a.y + b.y * b.y + c.y * c.y + d.y * d.y);
    local += (double)sqrtf(a.z * a.z + b.z * b.z + c.z * c.z + d.z * d.z);
    local += (double)sqrtf(a.w * a.w + b.w * b.w + c.w * c.w + d.w * d.w);
  }
#pragma unroll
  for (int off = 32; off > 0; off >>= 1) local += __shfl_down(local, off, 64);
  __shared__ double smem[4];
  const int lane = threadIdx.x & 63;
  const int wid = threadIdx.x >> 6;
  if (lane == 0) smem[wid] = local;
  __syncthreads();
  if (threadIdx.x == 0) {
    double s = smem[0] + smem[1] + smem[2] + smem[3];
    atomicAdd(acc, s);
  }
}

// diffX with swizzled-LDS scalar reads (addr(x)=x+(x>>6), <=2-way banks on
// every read/write). Writes ws planes 7..13. Near its BW floor (~19us).
__global__ __launch_bounds__(256) void k_dx(const float* __restrict__ y,
                                            const float* __restrict__ v,
                                            float* __restrict__ ws) {
  __shared__ float row[2120];  // 2088 padded floats, swizzle-expanded
  const int t = threadIdx.x;
  const int r = blockIdx.x;
  const int ch = blockIdx.y;  // 0..6 -> y0..y4, v0, v1
  const float* src = (ch < 5) ? (y + (size_t)ch * NHW) : (v + (size_t)(ch - 5) * NHW);
  const float* rp = src + (size_t)r * NW;

#define SWZ(i) ((i) + ((i) >> 6))
#define ST(i, val) { const int ii_ = (i); row[SWZ(ii_)] = (val); }

  const float4* rp4 = (const float4*)rp;
  float4 b0 = rp4[t];
  float4 b1 = rp4[t + 256];
  ST(RAD + 4 * t + 0, b0.x)
  ST(RAD + 4 * t + 1, b0.y)
  ST(RAD + 4 * t + 2, b0.z)
  ST(RAD + 4 * t + 3, b0.w)
  ST(RAD + 4 * (t + 256) + 0, b1.x)
  ST(RAD + 4 * (t + 256) + 1, b1.y)
  ST(RAD + 4 * (t + 256) + 2, b1.z)
  ST(RAD + 4 * (t + 256) + 3, b1.w)
  if (t < RAD) {
    ST(t, rp[RAD - t])                // left reflect (no edge repeat)
    ST(NW + RAD + t, rp[NW - 2 - t])  // right reflect
  }
  __syncthreads();

  const int xb = 8 * t;
  float r0 = 0.f, r1 = 0.f, r2 = 0.f, r3 = 0.f;
  float r4 = 0.f, r5 = 0.f, r6 = 0.f, r7 = 0.f;
#define RD(k) { const int x_ = xb + (k); float s_ = row[SWZ(x_)]; tap<(k)>(s_, R8); }
  RD(0)  RD(1)  RD(2)  RD(3)  RD(4)  RD(5)  RD(6)  RD(7)
  RD(8)  RD(9)  RD(10) RD(11) RD(12) RD(13) RD(14) RD(15)
  RD(16) RD(17) RD(18) RD(19) RD(20) RD(21) RD(22) RD(23)
  RD(24) RD(25) RD(26) RD(27) RD(28) RD(29) RD(30) RD(31)
  RD(32) RD(33) RD(34) RD(35) RD(36) RD(37) RD(38) RD(39)
  RD(40) RD(41) RD(42) RD(43) RD(44) RD(45) RD(46) RD(47)
#undef RD

  float4 o0, o1;
  o0.x = r0; o0.y = r1; o0.z = r2; o0.w = r3;
  o1.x = r4; o1.y = r5; o1.z = r6; o1.w = r7;
  float4* dst = (float4*)(ws + (size_t)(7 + ch) * NHW + (size_t)r * NW + xb);
  dst[0] = o0;
  dst[1] = o1;
}

// ---- Fused diffY + pointwise, 2-slot pipeline w/ global_load_lds ----
// Round-7 change: staging via __builtin_amdgcn_global_load_lds (4B/lane).
// Each staged row is 64 lanes x 4B contiguous; LDS dest = wave-uniform row
// base + lane*4 (wid wave-uniform) -> exactly the HW semantics (m104).
// Removes the 18-reg VGPR round trip + 18 ds_writes per step; loads fly
// async to LDS under the conv, drained by the step barrier's vmcnt(0).
// Race freedom unchanged: step i conv-reads slot i&1, stages slot (i+1)&1,
// whose last readers were sealed by step i-1's barrier.
__global__ __launch_bounds__(256, 4) void k_dyf(
    const float* __restrict__ y, const float* __restrict__ v,
    const float* __restrict__ gds, const float* __restrict__ cadc,
    const float* __restrict__ myoc, const float* __restrict__ ws,
    const double* __restrict__ acc, float* __restrict__ out) {
  __shared__ float tile[2 * TILE_CH];  // 36864 B
  const int lane = threadIdx.x & 63;
  const int wid = threadIdx.x >> 6;  // 0..3
  const int x0 = blockIdx.x * TW;
  const int yb = blockIdx.y * TH;
  const int base = wid * 8;

  const float m0 = (float)(acc[0] / (double)NHW);
  const float cad0 = fmaxf(cadc[0], 0.f);
  const float cad1 = fmaxf(cadc[1], 0.f);
  const float cad2 = fmaxf(cadc[2], 0.f);
  const float my0 = fmaxf(myoc[0], 0.f);
  const float my1 = fmaxf(myoc[1], 0.f);
  const float my2 = fmaxf(myoc[2], 0.f);
  const float my3 = fmaxf(myoc[3], 0.f);
  const float my4 = fmaxf(myoc[4], 0.f);

// One row: per-lane global src (contiguous), wave-uniform LDS row base.
#define GLL(g, k, srcp)                                                        \
  {                                                                            \
    const float* sp_ = (srcp) +                                                \
        (size_t)(((yb - RAD + wid + 4 * (k)) + NH) & (NH - 1)) * NW + x0 +     \
        lane;                                                                  \
    __builtin_amdgcn_global_load_lds(                                          \
        (const __attribute__((address_space(1))) void*)sp_,                    \
        (__attribute__((address_space(3))) void*)&tile[(g)*TILE_CH +           \
                                                       (wid + 4 * (k)) * TW],  \
        4, 0, 0);                                                              \
  }
#define STAGECH(g, srcp)                                                 \
  GLL(g, 0, srcp) GLL(g, 1, srcp) GLL(g, 2, srcp) GLL(g, 3, srcp)        \
  GLL(g, 4, srcp) GLL(g, 5, srcp) GLL(g, 6, srcp) GLL(g, 7, srcp)        \
  GLL(g, 8, srcp) GLL(g, 9, srcp) GLL(g, 10, srcp) GLL(g, 11, srcp)     \
  GLL(g, 12, srcp) GLL(g, 13, srcp) GLL(g, 14, srcp) GLL(g, 15, srcp)   \
  GLL(g, 16, srcp) GLL(g, 17, srcp)

#define DECL8(P)                                                       \
  float P##0 = 0.f, P##1 = 0.f, P##2 = 0.f, P##3 = 0.f, P##4 = 0.f,    \
        P##5 = 0.f, P##6 = 0.f, P##7 = 0.f;
#define CALLCONV(g, P)                                                  \
  conv_col(&tile[(g) * TILE_CH], base, lane, P##0, P##1, P##2, P##3,    \
           P##4, P##5, P##6, P##7);

  DECL8(ym00) DECL8(ym01) DECL8(ym10) DECL8(ym11)
  DECL8(yc) DECL8(yv0) DECL8(yv1)

  // Prologue: stage ch0 (m00) into slot 0.
  STAGECH(0, y)
  __syncthreads();  // vmcnt(0) drain -> slot0 ready
  // Step 0: issue m01 -> slot1; conv m00 (slot0).
  STAGECH(1, y + (size_t)NHW)
  CALLCONV(0, ym00)
  __syncthreads();
  // Step 1: issue m10 -> slot0; conv m01 (slot1).
  STAGECH(0, y + 2 * (size_t)NHW)
  CALLCONV(1, ym01)
  __syncthreads();
  // Step 2: issue m11 -> slot1; conv m10 (slot0).
  STAGECH(1, y + 3 * (size_t)NHW)
  CALLCONV(0, ym10)
  __syncthreads();
  // Step 3: issue c -> slot0; conv m11 (slot1).
  STAGECH(0, y + 4 * (size_t)NHW)
  CALLCONV(1, ym11)
  __syncthreads();
  // Step 4: issue v0 -> slot1; conv c (slot0).
  STAGECH(1, v)
  CALLCONV(0, yc)
  __syncthreads();
  // Step 5: issue v1 -> slot0; conv v0 (slot1).
  STAGECH(0, v + (size_t)NHW)
  CALLCONV(1, yv0)
  __syncthreads();
  // Step 6: conv v1 (slot0). No further staging, no barrier needed.
  CALLCONV(0, yv1)

  // Phase C: pointwise algebra per owned pixel (rows yb+base+q, col x0+lane).
  // m/c/v re-read from global: L2/L3-hot (this block staged them just now).
#define POINT(q)                                                              \
  {                                                                           \
    const size_t idx = (size_t)(yb + base + (q)) * NW + x0 + lane;            \
    const float m00 = y[idx];                                                 \
    const float m01 = y[idx + (size_t)NHW];                                   \
    const float m10 = y[idx + 2 * (size_t)NHW];                               \
    const float m11 = y[idx + 3 * (size_t)NHW];                               \
    const float c = y[idx + 4 * (size_t)NHW];                                 \
    const float v0 = v[idx];                                                  \
    const float v1 = v[idx + (size_t)NHW];                                    \
    const float g = gds[idx];                                                 \
    const float dY_m00 = ym00##q, dY_m01 = ym01##q;                           \
    const float dY_m10 = ym10##q, dY_m11 = ym11##q;                           \
    const float dY_c = yc##q, dY_v0 = yv0##q, dY_v1 = yv1##q;                 \
    const float dX_m00 = ws[idx + 7 * (size_t)NHW];                           \
    const float dX_m01 = ws[idx + 8 * (size_t)NHW];                           \
    const float dX_m10 = ws[idx + 9 * (size_t)NHW];                           \
    const float dX_m11 = ws[idx + 10 * (size_t)NHW];                          \
    const float dX_c = ws[idx + 11 * (size_t)NHW];                            \
    const float dX_v0 = ws[idx + 12 * (size_t)NHW];                           \
    const float dX_v1 = ws[idx + 13 * (size_t)NHW];                           \
    const float gv00 = dY_v0, gv01 = dX_v0, gv10 = dY_v1, gv11 = dX_v1;       \
    const float ww = -0.5f * (gv01 - gv10);                                   \
    const float E00 = gv00, E11 = gv11;                                       \
    const float E01 = 0.5f * (gv01 + gv10);                                   \
    const float E10 = E01;                                                    \
    const float trm = m00 + m11;                                              \
    const float dev00 = m00 - 0.5f * trm;                                     \
    const float dev01 = m01;                                                  \
    const float dev10 = m10;                                                  \
    const float dev11 = m11 - 0.5f * trm;                                     \
    const float dmag_sq =                                                     \
        dev00 * dev00 + dev01 * dev01 + dev10 * dev10 + dev11 * dev11;        \
    const float dm = sqrtf(dmag_sq);                                          \
    const float dm2 = dm * dm;                                                \
    const float devE = dev00 * E00 + dev01 * E01 + dev10 * E10 + dev11 * E11; \
    const float sg = (devE > 0.f) ? 1.f : ((devE < 0.f) ? -1.f : 0.f);        \
    const float coef = sg * devE / dm2;                                       \
    const float sc = 0.5f * dm / m0;                                          \
    const float Ea00 = (E00 - coef * dev00) * sc;                             \
    const float Ea01 = (E01 - coef * dev01) * sc;                             \
    const float Ea10 = (E10 - coef * dev10) * sc;                             \
    const float Ea11 = (E11 - coef * dev11) * sc;                             \
    const float Ep00 = E00 - Ea00;                                            \
    const float Ep01 = E01 - Ea01;                                            \
    const float Ep10 = E10 - Ea10;                                            \
    const float Ep11 = E11 - Ea11;                                            \
    const float mE00 = (m00 * Ep00 + m01 * Ep10) + (Ep00 * m00 + Ep01 * m10); \
    const float mE01 = (m00 * Ep01 + m01 * Ep11) + (Ep00 * m01 + Ep01 * m11); \
    const float mE10 = (m10 * Ep00 + m11 * Ep10) + (Ep10 * m00 + Ep11 * m10); \
    const float mE11 = (m10 * Ep01 + m11 * Ep11) + (Ep10 * m01 + Ep11 * m11); \
    const float divv = gv00 + gv11;                                           \
    const float cdot =                                                        \
        -(v0 * dY_c + v1 * dX_c) - cad0 * c + cad1 * c * divv + cad2 * g;     \
    const float md00 = -(v0 * dY_m00 + v1 * dX_m00) - ww * m10 - ww * m01 -   \
                       my0 * m00 + my1 * mE00 - my2 * c * mE00 + my3 * trm +  \
                       my4 * trm * m00;                                       \
    const float md01 = -(v0 * dY_m01 + v1 * dX_m01) - ww * m11 + ww * m00 -   \
                       my0 * m01 + my1 * mE01 - my2 * c * mE01 +              \
                       my4 * trm * m01;                                       \
    const float md10 = -(v0 * dY_m10 + v1 * dX_m10) + ww * m00 - ww * m11 -   \
                       my0 * m10 + my1 * mE10 - my2 * c * mE10 +              \
                       my4 * trm * m10;                                       \
    const float md11 = -(v0 * dY_m11 + v1 * dX_m11) + ww * m01 + ww * m10 -   \
                       my0 * m11 + my1 * mE11 - my2 * c * mE11 +              \
                       my4 * trm * m11;                                       \
    out[idx] = md00;                                                          \
    out[idx + (size_t)NHW] = md01;                                            \
    out[idx + 2 * (size_t)NHW] = md10;                                        \
    out[idx + 3 * (size_t)NHW] = md11;                                        \
    out[idx + 4 * (size_t)NHW] = cdot;                                        \
  }

  POINT(0) POINT(1) POINT(2) POINT(3)
  POINT(4) POINT(5) POINT(6) POINT(7)
#undef POINT
}

extern "C" void kernel_launch(void* const* d_in, const int* in_sizes, int n_in,
                              void* d_out, int out_size, void* d_ws, size_t ws_size,
                              hipStream_t stream) {
  (void)in_sizes; (void)n_in; (void)out_size; (void)ws_size;
  const float* y = (const float*)d_in[0];
  const float* v = (const float*)d_in[1];
  const float* gds = (const float*)d_in[2];
  const float* cadc = (const float*)d_in[3];
  const float* myoc = (const float*)d_in[4];
  float* out = (float*)d_out;

  double* acc = (double*)d_ws;                       // 8B accumulator
  float* planes = (float*)((char*)d_ws + 512);       // 14 x NHW fp32 planes (7..13 used)

  hipMemsetAsync(acc, 0, sizeof(double), stream);
  k_reduce<<<dim3(1024), dim3(256), 0, stream>>>(y, acc);
  k_dx<<<dim3(NH, 7), dim3(256), 0, stream>>>(y, v, planes);
  k_dyf<<<dim3(NW / TW, NH / TH), dim3(256), 0, stream>>>(y, v, gds, cadc, myoc,
                                                          planes, acc, out);
}